// Round 1
// baseline (168.053 us; speedup 1.0000x reference)
//
#include <hip/hip_runtime.h>

// Problem constants (from reference setup_inputs)
#define Bn 8
#define Nn 128
#define Fdim 32     // input feature dim F
#define Sdim 8      // edge feature dim S
#define Hdim 32     // kernel-network hidden width H
#define Fout 32     // output channels F_

// One block per (a,b) pair; 256 threads.
// out[a,b,c] = sum_{h,f} T[h,f]*W_out[h,c*32+f] + sum_f q[f]*b_out[c*32+f] + bias[c]
//   T[h,f] = sum_i fn[i]*relu(ef[a,b,i,:]@W0+b0)[h]*nf[a,i,f]
//   q[f]   = sum_i fn[i]*nf[a,i,f]
__global__ __launch_bounds__(256) void ecc_kernel(
    const float* __restrict__ nf,    // (B,N,F)
    const float* __restrict__ fltr,  // (B,N,N)
    const float* __restrict__ ef,    // (B,N,N,S)
    const float* __restrict__ W0,    // (S,H)
    const float* __restrict__ b0,    // (H)
    const float* __restrict__ Wout,  // (H, F_*F)
    const float* __restrict__ bout,  // (F_*F)
    const float* __restrict__ bias,  // (F_)
    float* __restrict__ out)         // (B,N,F_)
{
    __shared__ __align__(16) float nf_s[Nn * Fdim];   // 16 KB: nf[a,:,:]
    __shared__ float fn_s[Nn];                        // normalized filter row
    __shared__ float W0s[Sdim * Hdim];
    __shared__ float b0s[Hdim];
    __shared__ __align__(16) float efs[64];           // 8 i x 8 s chunk
    __shared__ float hbuf[8 * Hdim];                  // fn-scaled h for 8 i
    __shared__ __align__(16) float Ts[32 * 36];       // T[h][f], padded row 36
    __shared__ __align__(16) float qs[Fdim];
    __shared__ float red[256];
    __shared__ float inv_s;

    const int t   = threadIdx.x;
    const int blk = blockIdx.x;       // a*N + b
    const int a   = blk >> 7;

    // ---- stage nf[a] (4096 floats) via float4, coalesced ----
    {
        const float4* src = (const float4*)(nf + (size_t)a * Nn * Fdim);
        float4* dst = (float4*)nf_s;
        #pragma unroll
        for (int j = 0; j < 4; ++j) dst[j * 256 + t] = src[j * 256 + t];
    }
    if (t < Nn)          fn_s[t] = fltr[(size_t)blk * Nn + t];
    if (t < Sdim * Hdim) W0s[t]  = W0[t];
    if (t < Hdim)        b0s[t]  = b0[t];
    __syncthreads();

    // ---- row-normalize the filter ----
    if (t < 64) {
        float s = fn_s[t] + fn_s[t + 64];
        #pragma unroll
        for (int off = 32; off > 0; off >>= 1) s += __shfl_down(s, off);
        if (t == 0) inv_s = 1.0f / fmaxf(s, 1e-11f);
    }
    __syncthreads();
    if (t < Nn) fn_s[t] *= inv_s;
    __syncthreads();

    // ---- main loop: T[h, f] accumulation, thread owns h=t&31, f=(t>>5)*4+k ----
    const float* efrow = ef + (size_t)blk * (Nn * Sdim);   // 1024 contiguous floats
    float4 accT = make_float4(0.f, 0.f, 0.f, 0.f);

    for (int ic = 0; ic < 16; ++ic) {
        if (t < 64) efs[t] = efrow[ic * 64 + t];
        __syncthreads();
        // compute fn-scaled h for 8 i's: thread layout (il = t>>5, hcol = t&31)
        {
            const int il = t >> 5, hcol = t & 31;
            float acc = b0s[hcol];
            #pragma unroll
            for (int s = 0; s < Sdim; ++s) acc += efs[il * Sdim + s] * W0s[s * Hdim + hcol];
            hbuf[il * Hdim + hcol] = fmaxf(acc, 0.f) * fn_s[ic * 8 + il];
        }
        __syncthreads();
        // rank-8 update of T
        {
            const int h = t & 31, fq = t >> 5;
            #pragma unroll
            for (int il = 0; il < 8; ++il) {
                const int i = ic * 8 + il;
                const float hv = hbuf[il * Hdim + h];
                const float4 nv = *(const float4*)&nf_s[i * Fdim + fq * 4];
                accT.x += hv * nv.x; accT.y += hv * nv.y;
                accT.z += hv * nv.z; accT.w += hv * nv.w;
            }
        }
        __syncthreads();   // protect hbuf/efs before next chunk overwrite
    }

    // ---- write T to LDS; compute q on 32 lanes ----
    {
        const int h = t & 31, fq = t >> 5;
        *(float4*)&Ts[h * 36 + fq * 4] = accT;
    }
    if (t < Fdim) {
        float q = 0.f;
        #pragma unroll 4
        for (int i = 0; i < Nn; ++i) q += fn_s[i] * nf_s[i * Fdim + t];
        qs[t] = q;
    }
    __syncthreads();

    // ---- contract T against W_out: thread layout (c = t&31, g = t>>5 over h-groups) ----
    {
        const int c = t & 31, g = t >> 5;
        float partial = 0.f;
        #pragma unroll
        for (int hh = 0; hh < 4; ++hh) {
            const int h = g * 4 + hh;
            const float4* wrow = (const float4*)(Wout + (size_t)h * (Fout * Fdim) + c * Fdim);
            const float4* trow = (const float4*)&Ts[h * 36];
            #pragma unroll
            for (int f4 = 0; f4 < 8; ++f4) {
                const float4 tv = trow[f4];
                const float4 wv = wrow[f4];
                partial += tv.x * wv.x + tv.y * wv.y + tv.z * wv.z + tv.w * wv.w;
            }
        }
        red[t] = partial;
    }
    __syncthreads();

    // ---- final reduction + bias terms ----
    if (t < Fout) {
        float sres = bias[t];
        #pragma unroll
        for (int g = 0; g < 8; ++g) sres += red[g * 32 + t];
        const float4* brow = (const float4*)(bout + t * Fdim);
        const float4* qrow = (const float4*)qs;
        #pragma unroll
        for (int f4 = 0; f4 < 8; ++f4) {
            const float4 bv = brow[f4];
            const float4 qv = qrow[f4];
            sres += bv.x * qv.x + bv.y * qv.y + bv.z * qv.z + bv.w * qv.w;
        }
        out[(size_t)blk * Fout + t] = sres;
    }
}

extern "C" void kernel_launch(void* const* d_in, const int* in_sizes, int n_in,
                              void* d_out, int out_size, void* d_ws, size_t ws_size,
                              hipStream_t stream) {
    const float* nf   = (const float*)d_in[0];
    const float* fltr = (const float*)d_in[1];
    const float* ef   = (const float*)d_in[2];
    const float* W0   = (const float*)d_in[3];
    const float* b0   = (const float*)d_in[4];
    const float* Wout = (const float*)d_in[5];
    const float* bout = (const float*)d_in[6];
    const float* bias = (const float*)d_in[7];
    float* out = (float*)d_out;

    ecc_kernel<<<dim3(Bn * Nn), dim3(256), 0, stream>>>(
        nf, fltr, ef, W0, b0, Wout, bout, bias, out);
}

// Round 2
// 83.532 us; speedup vs baseline: 2.0119x; 2.0119x over previous
//
#include <hip/hip_runtime.h>

// Problem constants (from reference setup_inputs)
#define Bn 8
#define Nn 128
#define Fdim 32     // input feature dim F
#define Sdim 8      // edge feature dim S
#define Hdim 32     // kernel-network hidden width H
#define Fout 32     // output channels F_

// One block per (a,b); 256 threads; 3 barriers total.
// out[a,b,c] = inv * ( sum_{h,f} T'[h,f]*Wout[h,c*32+f] + sum_f q'[f]*bout[c*32+f] ) + bias[c]
//   T'[h,f] = sum_i fltr[i]*relu(ef[a,b,i,:]@W0+b0)[h]*nf[a,i,f]   (raw, un-normalized filter)
//   q'[f]   = sum_i fltr[i]*nf[a,i,f]
//   inv     = 1/max(sum_i fltr[i], 1e-11)
__global__ __launch_bounds__(256, 4) void ecc_kernel(
    const float* __restrict__ nf,    // (B,N,F)
    const float* __restrict__ fltr,  // (B,N,N)
    const float* __restrict__ ef,    // (B,N,N,S)
    const float* __restrict__ W0,    // (S,H)
    const float* __restrict__ b0,    // (H)
    const float* __restrict__ Wout,  // (H, F_*F)
    const float* __restrict__ bout,  // (F_*F)
    const float* __restrict__ bias,  // (F_)
    float* __restrict__ out)         // (B,N,F_)
{
    __shared__ __align__(16) float nf_s[Nn * Fdim];    // 16 KB  nf[a,:,:]
    __shared__ __align__(16) float hbuf[Nn * Hdim];    // 16 KB  fltr-scaled relu(h)
    __shared__ __align__(16) float efTs[Nn * Sdim];    // 4 KB   ef row; reused as Ts[32][32]
    __shared__ float fn_s[Nn];                         // raw filter row
    __shared__ __align__(16) float W0s[Sdim * Hdim];
    __shared__ float b0s[Hdim];
    __shared__ __align__(16) float qs[Fdim];
    __shared__ float inv_s;

    const int t   = threadIdx.x;
    const int blk = blockIdx.x;        // a*N + b
    const int a   = blk >> 7;

    // ---------- stage everything (coalesced) ----------
    {
        const float4* nsrc = (const float4*)(nf + (size_t)a * Nn * Fdim);
        float4* ndst = (float4*)nf_s;
        #pragma unroll
        for (int j = 0; j < 4; ++j) ndst[j * 256 + t] = nsrc[j * 256 + t];
        ((float4*)efTs)[t] = ((const float4*)(ef + (size_t)blk * Nn * Sdim))[t];
    }
    if (t < Nn)          fn_s[t] = fltr[(size_t)blk * Nn + t];
    if (t < Sdim * Hdim) W0s[t]  = W0[t];
    if (t < Hdim)        b0s[t]  = b0[t];
    __syncthreads();                                   // B1

    // ---------- inv = 1/sum(fltr row)  (wave 0 only, no barrier needed here) ----------
    if (t < 64) {
        float s = fn_s[t] + fn_s[t + 64];
        #pragma unroll
        for (int off = 32; off > 0; off >>= 1) s += __shfl_down(s, off);
        if (t == 0) inv_s = 1.0f / fmaxf(s, 1e-11f);
    }

    // ---------- h: hbuf[i*32+h] = relu(ef[i,:]@W0 + b0)[h] * fltr[i] ----------
    {
        const int hcol = t & 31, il = t >> 3 >> 2;     // il = t>>5 in 0..7
        #pragma unroll 4
        for (int k = 0; k < 16; ++k) {
            const int i = il * 16 + k;
            float acc = b0s[hcol];
            #pragma unroll
            for (int s = 0; s < Sdim; ++s)
                acc += efTs[i * Sdim + s] * W0s[s * Hdim + hcol];
            hbuf[i * Hdim + hcol] = fmaxf(acc, 0.0f) * fn_s[i];
        }
    }
    __syncthreads();                                   // B2

    // ---------- T'[h, fq*4..+4] accumulation (thread owns h=t&31, fq=t>>5) ----------
    {
        const int h = t & 31, fq = t >> 5;
        float4 accT = make_float4(0.f, 0.f, 0.f, 0.f);
        #pragma unroll 8
        for (int i = 0; i < Nn; ++i) {
            const float  hv = hbuf[i * Hdim + h];
            const float4 nv = *(const float4*)&nf_s[i * Fdim + fq * 4];
            accT.x += hv * nv.x; accT.y += hv * nv.y;
            accT.z += hv * nv.z; accT.w += hv * nv.w;
        }
        // Ts aliases efTs (ef dead after B2). Ts[h][f], stride 32 (bank-clean for epilogue).
        *(float4*)&efTs[h * Fdim + fq * 4] = accT;
    }
    // ---------- q' on the last 32 threads (concurrent with nothing else) ----------
    if (t >= 224) {
        const int f = t - 224;
        float q = 0.f;
        #pragma unroll 4
        for (int i = 0; i < Nn; ++i) q += fn_s[i] * nf_s[i * Fdim + f];
        qs[f] = q;
    }
    __syncthreads();                                   // B3

    // ---------- epilogue: out[c] = inv*(T'.Wout + q'.bout) + bias ----------
    // lane layout: c = t>>3 (32 c), f4 = t&7 -> Wout reads are contiguous 1KB per wave
    {
        const int c = t >> 3, f4 = t & 7;
        const float* wbase = Wout + (size_t)c * Fdim + f4 * 4;
        float partial = 0.f;
        #pragma unroll 4
        for (int h = 0; h < Hdim; ++h) {
            const float4 wv = *(const float4*)(wbase + (size_t)h * (Fout * Fdim));
            const float4 tv = *(const float4*)&efTs[h * Fdim + f4 * 4];
            partial += tv.x * wv.x + tv.y * wv.y + tv.z * wv.z + tv.w * wv.w;
        }
        {
            const float4 bv = *(const float4*)(bout + (size_t)c * Fdim + f4 * 4);
            const float4 qv = *(const float4*)&qs[f4 * 4];
            partial += qv.x * bv.x + qv.y * bv.y + qv.z * bv.z + qv.w * bv.w;
        }
        partial += __shfl_down(partial, 4, 8);
        partial += __shfl_down(partial, 2, 8);
        partial += __shfl_down(partial, 1, 8);
        if (f4 == 0)
            out[(size_t)blk * Fout + c] = partial * inv_s + bias[c];
    }
}

extern "C" void kernel_launch(void* const* d_in, const int* in_sizes, int n_in,
                              void* d_out, int out_size, void* d_ws, size_t ws_size,
                              hipStream_t stream) {
    const float* nf   = (const float*)d_in[0];
    const float* fltr = (const float*)d_in[1];
    const float* ef   = (const float*)d_in[2];
    const float* W0   = (const float*)d_in[3];
    const float* b0   = (const float*)d_in[4];
    const float* Wout = (const float*)d_in[5];
    const float* bout = (const float*)d_in[6];
    const float* bias = (const float*)d_in[7];
    float* out = (float*)d_out;

    ecc_kernel<<<dim3(Bn * Nn), dim3(256), 0, stream>>>(
        nf, fltr, ef, W0, b0, Wout, bout, bias, out);
}

// Round 3
// 80.740 us; speedup vs baseline: 2.0814x; 1.0346x over previous
//
#include <hip/hip_runtime.h>

// Problem constants (from reference setup_inputs)
#define Bn 8
#define Nn 128
#define Fdim 32     // input feature dim F
#define Sdim 8      // edge feature dim S
#define Hdim 32     // kernel-network hidden width H
#define Fout 32     // output channels F_

// One block per (a,b); 256 threads.
// out[a,b,c] = inv * ( sum_{h,f} T'[h,f]*Wout[h,c*32+f] + sum_f q'[f]*bout[c*32+f] ) + bias[c]
//   T'[h,f] = sum_i fltr[i]*relu(ef[a,b,i,:]@W0+b0)[h]*nf[a,i,f]
//   q'[f]   = sum_i fltr[i]*nf[a,i,f]
//   inv     = 1/max(sum_i fltr[i], 1e-11)
__global__ __launch_bounds__(256, 4) void ecc_kernel(
    const float* __restrict__ nf,    // (B,N,F)
    const float* __restrict__ fltr,  // (B,N,N)
    const float* __restrict__ ef,    // (B,N,N,S)
    const float* __restrict__ W0,    // (S,H)
    const float* __restrict__ b0,    // (H)
    const float* __restrict__ Wout,  // (H, F_*F)
    const float* __restrict__ bout,  // (F_*F)
    const float* __restrict__ bias,  // (F_)
    float* __restrict__ out)         // (B,N,F_)
{
    __shared__ __align__(16) float nf_s[Nn * Fdim];   // 16 KB  nf[a,:,:]
    __shared__ __align__(16) float hbuf[Nn * Hdim];   // 16 KB  fltr-scaled relu(h); first 4KB reused as Ts[32][32]
    __shared__ __align__(16) float efs[Nn * Sdim];    // 4 KB   ef row; reused as T-partials (128 x 8 floats)
    __shared__ __align__(16) float qp[Nn];            // 512 B  q partials (4 quarters x 32 f)
    __shared__ float fn_s[Nn];                        // raw filter row
    __shared__ float inv_s;

    const int t    = threadIdx.x;
    const int blk  = blockIdx.x;       // a*N + b
    const int a    = blk >> 7;
    const int hcol = t & 31;

    // ---- register preloads (global; independent of LDS; overlap with staging) ----
    float w0r[8];
    #pragma unroll
    for (int s = 0; s < Sdim; ++s) w0r[s] = W0[s * Hdim + hcol];
    const float b0r = b0[hcol];

    // ---- stage nf[a], ef row, fltr row (coalesced) ----
    {
        const float4* nsrc = (const float4*)(nf + (size_t)a * Nn * Fdim);
        float4* ndst = (float4*)nf_s;
        #pragma unroll
        for (int j = 0; j < 4; ++j) ndst[j * 256 + t] = nsrc[j * 256 + t];
        ((float4*)efs)[t] = ((const float4*)(ef + (size_t)blk * Nn * Sdim))[t];
    }
    if (t < Nn) fn_s[t] = fltr[(size_t)blk * Nn + t];
    __syncthreads();                                   // B1

    // ---- inv = 1/sum(fltr row)  (wave 0; visible by B3) ----
    if (t < 64) {
        float s = fn_s[t] + fn_s[t + 64];
        #pragma unroll
        for (int off = 32; off > 0; off >>= 1) s += __shfl_down(s, off);
        if (t == 0) inv_s = 1.0f / fmaxf(s, 1e-11f);
    }

    // ---- h: hbuf[i*32+h] = relu(ef[i,:]@W0 + b0)[h] * fltr[i]  (W0 in regs) ----
    {
        const int il = t >> 5;                         // 0..7
        #pragma unroll 4
        for (int k = 0; k < 16; ++k) {
            const int i = il * 16 + k;
            const float4 e0 = *(const float4*)&efs[i * Sdim];
            const float4 e1 = *(const float4*)&efs[i * Sdim + 4];
            float acc = b0r;
            acc += e0.x * w0r[0] + e0.y * w0r[1] + e0.z * w0r[2] + e0.w * w0r[3];
            acc += e1.x * w0r[4] + e1.y * w0r[5] + e1.z * w0r[6] + e1.w * w0r[7];
            hbuf[i * Hdim + hcol] = fmaxf(acc, 0.0f) * fn_s[i];
        }
    }
    __syncthreads();                                   // B2

    // ---- T-accum: thread owns (2 h, 4 f); i-range split across thread halves ----
    const int fq   = t & 7;                            // f-quad 0..7
    const int h0   = ((t >> 3) & 15) * 2;              // h pair base 0,2,..,30
    const int half = t >> 7;                           // 0 or 1
    float4 acc0 = make_float4(0.f, 0.f, 0.f, 0.f);
    float4 acc1 = make_float4(0.f, 0.f, 0.f, 0.f);
    {
        const int ibase = half * 64;
        #pragma unroll 8
        for (int k = 0; k < 64; ++k) {
            const int i = ibase + k;
            const float2 hv = *(const float2*)&hbuf[i * Hdim + h0];
            const float4 nv = *(const float4*)&nf_s[i * Fdim + fq * 4];
            acc0.x += hv.x * nv.x; acc0.y += hv.x * nv.y;
            acc0.z += hv.x * nv.z; acc0.w += hv.x * nv.w;
            acc1.x += hv.y * nv.x; acc1.y += hv.y * nv.y;
            acc1.z += hv.y * nv.z; acc1.w += hv.y * nv.w;
        }
    }
    if (half) {   // upper half: park partials in efs (dead after B2)
        float4* p = (float4*)&efs[(t - 128) * 8];
        p[0] = acc0; p[1] = acc1;
    }
    __syncthreads();                                   // B2.5

    if (!half) {  // lower half: combine + write Ts (reuse hbuf rows 0..31)
        const float4* p = (const float4*)&efs[t * 8];
        const float4 p0 = p[0], p1 = p[1];
        acc0.x += p0.x; acc0.y += p0.y; acc0.z += p0.z; acc0.w += p0.w;
        acc1.x += p1.x; acc1.y += p1.y; acc1.z += p1.z; acc1.w += p1.w;
        *(float4*)&hbuf[h0 * Fdim + fq * 4]       = acc0;
        *(float4*)&hbuf[(h0 + 1) * Fdim + fq * 4] = acc1;
    } else {      // upper half: q' partials (4-way i-split over 32 f)
        const int f = t & 31, qr = (t >> 5) & 3;
        float q = 0.f;
        #pragma unroll 4
        for (int k = 0; k < 32; ++k) {
            const int i = qr * 32 + k;
            q += fn_s[i] * nf_s[i * Fdim + f];
        }
        qp[qr * 32 + f] = q;
    }
    __syncthreads();                                   // B3

    // ---- epilogue: out[c] = inv*(Ts.Wout + q'.bout) + bias ----
    // lane layout: c = t>>3, f4 = t&7 -> Wout reads contiguous 1KB per wave per h
    {
        const int c = t >> 3, f4 = t & 7;
        const float* wbase = Wout + (size_t)c * Fdim + f4 * 4;
        float partial = 0.f;
        #pragma unroll 8
        for (int h = 0; h < Hdim; ++h) {
            const float4 wv = *(const float4*)(wbase + (size_t)h * (Fout * Fdim));
            const float4 tv = *(const float4*)&hbuf[h * Fdim + f4 * 4];
            partial += tv.x * wv.x + tv.y * wv.y + tv.z * wv.z + tv.w * wv.w;
        }
        {
            const float4 q0 = *(const float4*)&qp[f4 * 4];
            const float4 q1 = *(const float4*)&qp[32 + f4 * 4];
            const float4 q2 = *(const float4*)&qp[64 + f4 * 4];
            const float4 q3 = *(const float4*)&qp[96 + f4 * 4];
            const float4 bv = *(const float4*)(bout + (size_t)c * Fdim + f4 * 4);
            partial += (q0.x + q1.x + q2.x + q3.x) * bv.x;
            partial += (q0.y + q1.y + q2.y + q3.y) * bv.y;
            partial += (q0.z + q1.z + q2.z + q3.z) * bv.z;
            partial += (q0.w + q1.w + q2.w + q3.w) * bv.w;
        }
        partial += __shfl_down(partial, 4, 8);
        partial += __shfl_down(partial, 2, 8);
        partial += __shfl_down(partial, 1, 8);
        if (f4 == 0)
            out[(size_t)blk * Fout + c] = partial * inv_s + bias[c];
    }
}

extern "C" void kernel_launch(void* const* d_in, const int* in_sizes, int n_in,
                              void* d_out, int out_size, void* d_ws, size_t ws_size,
                              hipStream_t stream) {
    const float* nf   = (const float*)d_in[0];
    const float* fltr = (const float*)d_in[1];
    const float* ef   = (const float*)d_in[2];
    const float* W0   = (const float*)d_in[3];
    const float* b0   = (const float*)d_in[4];
    const float* Wout = (const float*)d_in[5];
    const float* bout = (const float*)d_in[6];
    const float* bias = (const float*)d_in[7];
    float* out = (float*)d_out;

    ecc_kernel<<<dim3(Bn * Nn), dim3(256), 0, stream>>>(
        nf, fltr, ef, W0, b0, Wout, bout, bias, out);
}